// Round 4
// baseline (968.442 us; speedup 1.0000x reference)
//
#include <hip/hip_runtime.h>

// Resonance tiling: y1 = x1 + Ham(x2, phi[:8]); y2 = x2 + Ham(y1, psi[8:])
// x: [65536, 256, 4] f32. Weights [16,16,16,4] f32. Per-(row,tile) local.
//
// Round-3: 157us, no pipe >41% real -> latency-bound (one serial FMA chain
// per wave, 5.3 waves/SIMD). This round:
//  - R=2 rows/thread: two independent FMA chains (ILP), weight LDS reads
//    amortized x2, loop overhead halved per row.
//  - one LDS buffer reused x2->y1 (wave-local, program-ordered overwrite).
//  - x1 not held across iters: load issued at stage-1 top, added at stage-1
//    END (~1000cyc cover) -> fewer live VGPRs.
//  - __launch_bounds__(256,8): cap 64 VGPR = 8 waves/SIMD (occupancy quantum
//    halves past 64 per m69 -> 64 is the cliff edge).

__device__ __forceinline__ void ham_acc(float4& r, const float4 x, const float4 w) {
    r.x = fmaf(x.x,  w.x, r.x); r.x = fmaf(x.y, -w.y, r.x);
    r.x = fmaf(x.z, -w.z, r.x); r.x = fmaf(x.w, -w.w, r.x);
    r.y = fmaf(x.x,  w.y, r.y); r.y = fmaf(x.y,  w.x, r.y);
    r.y = fmaf(x.z,  w.w, r.y); r.y = fmaf(x.w, -w.z, r.y);
    r.z = fmaf(x.x,  w.z, r.z); r.z = fmaf(x.y, -w.w, r.z);
    r.z = fmaf(x.z,  w.x, r.z); r.z = fmaf(x.w,  w.y, r.z);
    r.w = fmaf(x.x,  w.w, r.w); r.w = fmaf(x.y,  w.z, r.w);
    r.w = fmaf(x.z, -w.y, r.w); r.w = fmaf(x.w,  w.x, r.w);
}

#define W_LIST(F) F(0) F(1) F(2) F(3) F(4) F(5) F(6) F(7) \
                  F(8) F(9) F(10) F(11) F(12) F(13) F(14) F(15)

__global__ __launch_bounds__(256, 8)
void resonance_kernel(const float4* __restrict__ x,
                      const float4* __restrict__ phi,
                      const float4* __restrict__ psi,
                      float4* __restrict__ out,
                      int ngroups) {
    __shared__ float4 wphi[256];      // phi[t][i][j]
    __shared__ float4 wpsi[256];      // psi[8+t][i][j]
    __shared__ float4 xbuf[32][17];   // x2 then y1; pad 17 -> conflict-free

    const int tid = threadIdx.x;
    const int t   = blockIdx.x & 7;
    const int rl  = tid >> 4;         // 0..15 (wave-local slot pairs rl, rl+16)
    const int j   = tid & 15;

    wphi[tid] = phi[t * 256 + tid];
    wpsi[tid] = psi[(8 + t) * 256 + tid];
    __syncthreads();                  // weights ready (only block-wide sync)

    const int gstride = gridDim.x >> 3;
    int g = blockIdx.x >> 3;

    const int col1 = t * 16 + j;      // y1/x1 column (float4 index in row)
    const int col2 = 128 + col1;      // y2/x2 column

    float4 a2, b2;                    // x2 of row A = g*32+rl, row B = +16
    if (g < ngroups) {
        const size_t rA = (size_t)g * 32 + rl;
        a2 = x[rA * 256 + col2];
        b2 = x[(rA + 16) * 256 + col2];
    }

    while (g < ngroups) {
        xbuf[rl][j]      = a2;
        xbuf[rl + 16][j] = b2;
        __builtin_amdgcn_wave_barrier();

        const size_t rA = (size_t)g * 32 + rl;

        // issue x1 loads now; consumed at END of stage 1 (latency covered)
        const float4 c1A = x[rA * 256 + col1];
        const float4 c1B = x[(rA + 16) * 256 + col1];

        // prefetch next-iter x2
        const int gn = g + gstride;
        float4 na2, nb2;
        if (gn < ngroups) {
            const size_t rN = (size_t)gn * 32 + rl;
            na2 = x[rN * 256 + col2];
            nb2 = x[(rN + 16) * 256 + col2];
        }

        // ---- stage 1: y1 = x1 + sum_i Ham(x2[i], phi[i][j]) ----
        float4 accA = make_float4(0.f, 0.f, 0.f, 0.f);
        float4 accB = make_float4(0.f, 0.f, 0.f, 0.f);
#define S1(i) { const float4 w = wphi[(i) * 16 + j]; \
                ham_acc(accA, xbuf[rl][(i)], w); \
                ham_acc(accB, xbuf[rl + 16][(i)], w); }
        W_LIST(S1)
#undef S1
        accA.x += c1A.x; accA.y += c1A.y; accA.z += c1A.z; accA.w += c1A.w;
        accB.x += c1B.x; accB.y += c1B.y; accB.z += c1B.z; accB.w += c1B.w;
        out[rA * 256 + col1]        = accA;
        out[(rA + 16) * 256 + col1] = accB;

        __builtin_amdgcn_wave_barrier();
        xbuf[rl][j]      = accA;          // y1 overwrites x2 (wave-local)
        xbuf[rl + 16][j] = accB;
        __builtin_amdgcn_wave_barrier();

        // ---- stage 2: y2 = x2 + sum_i Ham(y1[i], psi[i][j]) ----
        float4 accA2 = a2, accB2 = b2;
#define S2(i) { const float4 w = wpsi[(i) * 16 + j]; \
                ham_acc(accA2, xbuf[rl][(i)], w); \
                ham_acc(accB2, xbuf[rl + 16][(i)], w); }
        W_LIST(S2)
#undef S2
        out[rA * 256 + col2]        = accA2;
        out[(rA + 16) * 256 + col2] = accB2;

        a2 = na2; b2 = nb2;
        g = gn;
    }
}

extern "C" void kernel_launch(void* const* d_in, const int* in_sizes, int n_in,
                              void* d_out, int out_size, void* d_ws, size_t ws_size,
                              hipStream_t stream) {
    const float4* x   = (const float4*)d_in[0];
    const float4* phi = (const float4*)d_in[1];
    const float4* psi = (const float4*)d_in[2];
    float4* out = (float4*)d_out;

    const int rows    = in_sizes[0] / (256 * 4);   // 65536
    const int ngroups = rows / 32;                 // 2048 groups of 32 rows
    const int blocks  = 8 * 512;                   // tile = bid&7, chunk = bid>>3

    resonance_kernel<<<blocks, 256, 0, stream>>>(x, phi, psi, out, ngroups);
}

// Round 5
// 509.009 us; speedup vs baseline: 1.9026x; 1.9026x over previous
//
#include <hip/hip_runtime.h>

// Resonance tiling: y1 = x1 + Ham(x2, phi[:8]); y2 = x2 + Ham(y1, psi[8:])
// x: [65536, 256, 4] f32. Weights [16,16,16,4] f32. Per-(row,tile) local.
//
// Round-4 post-mortem: __launch_bounds__(256,8) (<=64 VGPR) spilled the R=2
// live set to scratch (FETCH 1.28GB, WRITE 2.4GB, 968us). Same kernel with
// (256,4): cap 128 VGPR -> no spill, keep the two independent FMA chains.
//  - R=2 rows/thread: ILP (two chains), weight LDS reads amortized x2.
//  - one LDS buffer reused x2->y1 (wave-local, program-ordered overwrite).
//  - x1 loaded at stage-1 top, added at stage-1 END (latency covered).
//  - block = one tile (t=bid&7); no __syncthreads in loop.

__device__ __forceinline__ void ham_acc(float4& r, const float4 x, const float4 w) {
    r.x = fmaf(x.x,  w.x, r.x); r.x = fmaf(x.y, -w.y, r.x);
    r.x = fmaf(x.z, -w.z, r.x); r.x = fmaf(x.w, -w.w, r.x);
    r.y = fmaf(x.x,  w.y, r.y); r.y = fmaf(x.y,  w.x, r.y);
    r.y = fmaf(x.z,  w.w, r.y); r.y = fmaf(x.w, -w.z, r.y);
    r.z = fmaf(x.x,  w.z, r.z); r.z = fmaf(x.y, -w.w, r.z);
    r.z = fmaf(x.z,  w.x, r.z); r.z = fmaf(x.w,  w.y, r.z);
    r.w = fmaf(x.x,  w.w, r.w); r.w = fmaf(x.y,  w.z, r.w);
    r.w = fmaf(x.z, -w.y, r.w); r.w = fmaf(x.w,  w.x, r.w);
}

#define W_LIST(F) F(0) F(1) F(2) F(3) F(4) F(5) F(6) F(7) \
                  F(8) F(9) F(10) F(11) F(12) F(13) F(14) F(15)

__global__ __launch_bounds__(256, 4)
void resonance_kernel(const float4* __restrict__ x,
                      const float4* __restrict__ phi,
                      const float4* __restrict__ psi,
                      float4* __restrict__ out,
                      int ngroups) {
    __shared__ float4 wphi[256];      // phi[t][i][j]
    __shared__ float4 wpsi[256];      // psi[8+t][i][j]
    __shared__ float4 xbuf[32][17];   // x2 then y1; pad 17 -> conflict-free

    const int tid = threadIdx.x;
    const int t   = blockIdx.x & 7;
    const int rl  = tid >> 4;         // 0..15 (wave-local slot pairs rl, rl+16)
    const int j   = tid & 15;

    wphi[tid] = phi[t * 256 + tid];
    wpsi[tid] = psi[(8 + t) * 256 + tid];
    __syncthreads();                  // weights ready (only block-wide sync)

    const int gstride = gridDim.x >> 3;
    int g = blockIdx.x >> 3;

    const int col1 = t * 16 + j;      // y1/x1 column (float4 index in row)
    const int col2 = 128 + col1;      // y2/x2 column

    float4 a2, b2;                    // x2 of row A = g*32+rl, row B = +16
    if (g < ngroups) {
        const size_t rA = (size_t)g * 32 + rl;
        a2 = x[rA * 256 + col2];
        b2 = x[(rA + 16) * 256 + col2];
    }

    while (g < ngroups) {
        xbuf[rl][j]      = a2;
        xbuf[rl + 16][j] = b2;
        __builtin_amdgcn_wave_barrier();

        const size_t rA = (size_t)g * 32 + rl;

        // issue x1 loads now; consumed at END of stage 1 (latency covered)
        const float4 c1A = x[rA * 256 + col1];
        const float4 c1B = x[(rA + 16) * 256 + col1];

        // prefetch next-iter x2
        const int gn = g + gstride;
        float4 na2, nb2;
        if (gn < ngroups) {
            const size_t rN = (size_t)gn * 32 + rl;
            na2 = x[rN * 256 + col2];
            nb2 = x[(rN + 16) * 256 + col2];
        }

        // ---- stage 1: y1 = x1 + sum_i Ham(x2[i], phi[i][j]) ----
        float4 accA = make_float4(0.f, 0.f, 0.f, 0.f);
        float4 accB = make_float4(0.f, 0.f, 0.f, 0.f);
#define S1(i) { const float4 w = wphi[(i) * 16 + j]; \
                ham_acc(accA, xbuf[rl][(i)], w); \
                ham_acc(accB, xbuf[rl + 16][(i)], w); }
        W_LIST(S1)
#undef S1
        accA.x += c1A.x; accA.y += c1A.y; accA.z += c1A.z; accA.w += c1A.w;
        accB.x += c1B.x; accB.y += c1B.y; accB.z += c1B.z; accB.w += c1B.w;
        out[rA * 256 + col1]        = accA;
        out[(rA + 16) * 256 + col1] = accB;

        __builtin_amdgcn_wave_barrier();
        xbuf[rl][j]      = accA;          // y1 overwrites x2 (wave-local)
        xbuf[rl + 16][j] = accB;
        __builtin_amdgcn_wave_barrier();

        // ---- stage 2: y2 = x2 + sum_i Ham(y1[i], psi[i][j]) ----
        float4 accA2 = a2, accB2 = b2;
#define S2(i) { const float4 w = wpsi[(i) * 16 + j]; \
                ham_acc(accA2, xbuf[rl][(i)], w); \
                ham_acc(accB2, xbuf[rl + 16][(i)], w); }
        W_LIST(S2)
#undef S2
        out[rA * 256 + col2]        = accA2;
        out[(rA + 16) * 256 + col2] = accB2;

        a2 = na2; b2 = nb2;
        g = gn;
    }
}

extern "C" void kernel_launch(void* const* d_in, const int* in_sizes, int n_in,
                              void* d_out, int out_size, void* d_ws, size_t ws_size,
                              hipStream_t stream) {
    const float4* x   = (const float4*)d_in[0];
    const float4* phi = (const float4*)d_in[1];
    const float4* psi = (const float4*)d_in[2];
    float4* out = (float4*)d_out;

    const int rows    = in_sizes[0] / (256 * 4);   // 65536
    const int ngroups = rows / 32;                 // 2048 groups of 32 rows
    const int blocks  = 8 * 512;                   // tile = bid&7, chunk = bid>>3

    resonance_kernel<<<blocks, 256, 0, stream>>>(x, phi, psi, out, ngroups);
}

// Round 6
// 153.253 us; speedup vs baseline: 6.3192x; 3.3214x over previous
//
#include <hip/hip_runtime.h>

// Resonance tiling: y1 = x1 + Ham(x2, phi[:8]); y2 = x2 + Ham(y1, psi[8:])
// x: [65536, 256, 4] f32. Weights [16,16,16,4] f32. Per-(row,tile) local.
//
// Round-5 post-mortem: rocprof VGPR_Count is ~real/2 on gfx950; R=2 live set
// overflowed the 128-real cap -> spill (WRITE 1.25GB). This round: R=2 with a
// SLIM live set (~12 float4) to fit the 64-real tier:
//  - separate y1s buffer; stage-2 "+x2" re-read from LDS -> a2/b2 die early
//  - acc initialized from x1 (no deferred add) -> c1A/c1B die at init
//  - NO global prefetch; 6 waves/SIMD (LDS-capped) hide latency instead
//  - weight LDS reads amortized over 2 rows; no __syncthreads in loop

__device__ __forceinline__ void ham_acc(float4& r, const float4 x, const float4 w) {
    r.x = fmaf(x.x,  w.x, r.x); r.x = fmaf(x.y, -w.y, r.x);
    r.x = fmaf(x.z, -w.z, r.x); r.x = fmaf(x.w, -w.w, r.x);
    r.y = fmaf(x.x,  w.y, r.y); r.y = fmaf(x.y,  w.x, r.y);
    r.y = fmaf(x.z,  w.w, r.y); r.y = fmaf(x.w, -w.z, r.y);
    r.z = fmaf(x.x,  w.z, r.z); r.z = fmaf(x.y, -w.w, r.z);
    r.z = fmaf(x.z,  w.x, r.z); r.z = fmaf(x.w,  w.y, r.z);
    r.w = fmaf(x.x,  w.w, r.w); r.w = fmaf(x.y,  w.z, r.w);
    r.w = fmaf(x.z, -w.y, r.w); r.w = fmaf(x.w,  w.x, r.w);
}

#define W_LIST(F) F(0) F(1) F(2) F(3) F(4) F(5) F(6) F(7) \
                  F(8) F(9) F(10) F(11) F(12) F(13) F(14) F(15)

__global__ __launch_bounds__(256, 4)
void resonance_kernel(const float4* __restrict__ x,
                      const float4* __restrict__ phi,
                      const float4* __restrict__ psi,
                      float4* __restrict__ out,
                      int ngroups) {
    __shared__ float4 wphi[256];      // phi[t][i][j]
    __shared__ float4 wpsi[256];      // psi[8+t][i][j]
    __shared__ float4 xbuf[32][17];   // x2 rows (pad 17 -> conflict-free)
    __shared__ float4 y1s[32][17];    // y1 rows

    const int tid = threadIdx.x;
    const int t   = blockIdx.x & 7;
    const int rl  = tid >> 4;         // 0..15; wave owns rows rl(4) and rl+16
    const int j   = tid & 15;

    wphi[tid] = phi[t * 256 + tid];
    wpsi[tid] = psi[(8 + t) * 256 + tid];
    __syncthreads();                  // weights ready (only block-wide sync)

    const int gstride = gridDim.x >> 3;
    int g = blockIdx.x >> 3;

    const int col1 = t * 16 + j;      // x1/y1 column (float4 index in row)
    const int col2 = 128 + col1;      // x2/y2 column

    while (g < ngroups) {
        const size_t rA = (size_t)g * 32 + rl;     // rows rA and rA+16

        // x2 loads -> LDS; a2/b2 die at the write
        {
            const float4 a2 = x[rA * 256 + col2];
            const float4 b2 = x[(rA + 16) * 256 + col2];
            xbuf[rl][j]      = a2;
            xbuf[rl + 16][j] = b2;
        }
        __builtin_amdgcn_wave_barrier();

        // ---- stage 1: y1 = x1 + sum_i Ham(x2[i], phi[i][j]) ----
        float4 accA = x[rA * 256 + col1];          // init = x1 (dies into acc)
        float4 accB = x[(rA + 16) * 256 + col1];
#define S1(i) { const float4 w = wphi[(i) * 16 + j]; \
                ham_acc(accA, xbuf[rl][(i)], w); \
                ham_acc(accB, xbuf[rl + 16][(i)], w); }
        W_LIST(S1)
#undef S1
        out[rA * 256 + col1]        = accA;
        out[(rA + 16) * 256 + col1] = accB;
        y1s[rl][j]      = accA;
        y1s[rl + 16][j] = accB;
        __builtin_amdgcn_wave_barrier();

        // ---- stage 2: y2 = x2 + sum_i Ham(y1[i], psi[i][j]) ----
        float4 accA2 = xbuf[rl][j];                // = x2 (from LDS, cheap)
        float4 accB2 = xbuf[rl + 16][j];
#define S2(i) { const float4 w = wpsi[(i) * 16 + j]; \
                ham_acc(accA2, y1s[rl][(i)], w); \
                ham_acc(accB2, y1s[rl + 16][(i)], w); }
        W_LIST(S2)
#undef S2
        out[rA * 256 + col2]        = accA2;
        out[(rA + 16) * 256 + col2] = accB2;

        g += gstride;
    }
}

extern "C" void kernel_launch(void* const* d_in, const int* in_sizes, int n_in,
                              void* d_out, int out_size, void* d_ws, size_t ws_size,
                              hipStream_t stream) {
    const float4* x   = (const float4*)d_in[0];
    const float4* phi = (const float4*)d_in[1];
    const float4* psi = (const float4*)d_in[2];
    float4* out = (float4*)d_out;

    const int rows    = in_sizes[0] / (256 * 4);   // 65536
    const int ngroups = rows / 32;                 // 2048 groups of 32 rows
    const int blocks  = 8 * 512;                   // tile = bid&7, chunk = bid>>3

    resonance_kernel<<<blocks, 256, 0, stream>>>(x, phi, psi, out, ngroups);
}

// Round 7
// 143.940 us; speedup vs baseline: 6.7281x; 1.0647x over previous
//
#include <hip/hip_runtime.h>

// Resonance tiling via fused block-GEMM on MFMA.
// Math: per tile t (quaternion Hamilton product = real 4x4 blocks):
//   y1 = x1 + x2*Phi_t ; y2 = x2 + y1*Psi_t  (row-vec x matrix, 64x64 real)
// Fused: [y1,y2] = [x1,x2] * M_t,  M_t = [[I, Psi],[Phi, I+Phi*Psi]] (128x128).
// prep_kernel builds M_t^T in bf16 into d_ws (8*128*128*2B = 256KB).
// gemm_kernel: block = 128 rows x 1 tile; X f32->bf16 -> LDS (XOR-swizzled);
// M^T fragments in VGPRs; 64x mfma_f32_16x16x32_bf16; f32 stores.
// bf16 error ~|x|*2^-9 ~= 0.03 absmax << 0.11 threshold.

typedef __attribute__((ext_vector_type(8))) short bf16x8;
typedef __attribute__((ext_vector_type(4))) float f32x4;

static __device__ __forceinline__ unsigned short f2bf(float f) {
    unsigned u = __builtin_bit_cast(unsigned, f);
    unsigned r = 0x7FFFu + ((u >> 16) & 1u);     // round-to-nearest-even
    return (unsigned short)((u + r) >> 16);
}

// ---------------- pre-kernel: build M_t^T (bf16) ----------------
__global__ __launch_bounds__(256)
void prep_kernel(const float4* __restrict__ phi,
                 const float4* __restrict__ psi,
                 unsigned short* __restrict__ mt) {
    __shared__ float Phi[64][64];
    __shared__ float Psi[64][64];
    const int t   = blockIdx.x;          // 0..7
    const int tid = threadIdx.x;
    const int i   = tid >> 4, j = tid & 15;

    {   // Hamilton 4x4 block of phi[t][i][j] (row-vec convention, matches ref)
        float4 w = phi[t * 256 + i * 16 + j];
        float a = w.x, b = w.y, c = w.z, d = w.w;
        Phi[4*i+0][4*j+0]= a; Phi[4*i+0][4*j+1]= b; Phi[4*i+0][4*j+2]= c; Phi[4*i+0][4*j+3]= d;
        Phi[4*i+1][4*j+0]=-b; Phi[4*i+1][4*j+1]= a; Phi[4*i+1][4*j+2]=-d; Phi[4*i+1][4*j+3]= c;
        Phi[4*i+2][4*j+0]=-c; Phi[4*i+2][4*j+1]= d; Phi[4*i+2][4*j+2]= a; Phi[4*i+2][4*j+3]=-b;
        Phi[4*i+3][4*j+0]=-d; Phi[4*i+3][4*j+1]=-c; Phi[4*i+3][4*j+2]= b; Phi[4*i+3][4*j+3]= a;
        float4 v = psi[(8 + t) * 256 + i * 16 + j];
        a = v.x; b = v.y; c = v.z; d = v.w;
        Psi[4*i+0][4*j+0]= a; Psi[4*i+0][4*j+1]= b; Psi[4*i+0][4*j+2]= c; Psi[4*i+0][4*j+3]= d;
        Psi[4*i+1][4*j+0]=-b; Psi[4*i+1][4*j+1]= a; Psi[4*i+1][4*j+2]=-d; Psi[4*i+1][4*j+3]= c;
        Psi[4*i+2][4*j+0]=-c; Psi[4*i+2][4*j+1]= d; Psi[4*i+2][4*j+2]= a; Psi[4*i+2][4*j+3]=-b;
        Psi[4*i+3][4*j+0]=-d; Psi[4*i+3][4*j+1]=-c; Psi[4*i+3][4*j+2]= b; Psi[4*i+3][4*j+3]= a;
    }
    __syncthreads();

    unsigned short* m = mt + t * 16384;   // MT[n][k] = M[k][n]
    // quadrants except M22
    for (int e = tid; e < 16384; e += 256) {
        const int n = e >> 7, k = e & 127;
        if (n >= 64 && k >= 64) continue;
        float v;
        if (k < 64 && n < 64)       v = (k == n) ? 1.f : 0.f;   // M11 = I
        else if (k >= 64)           v = Phi[k - 64][n];          // M21 = Phi
        else                        v = Psi[k][n - 64];          // M12 = Psi
        m[e] = f2bf(v);
    }
    // M22 = I + Phi@Psi : thread computes P[r][c0..c0+15]
    const int r = tid & 63, c0 = (tid >> 6) * 16;
    float pk[16];
#pragma unroll
    for (int cc = 0; cc < 16; ++cc) pk[cc] = 0.f;
    for (int k = 0; k < 64; ++k) {
        const float fr = Phi[r][k];
#pragma unroll
        for (int cc = 0; cc < 16; ++cc) pk[cc] = fmaf(fr, Psi[k][c0 + cc], pk[cc]);
    }
#pragma unroll
    for (int cc = 0; cc < 16; ++cc) {
        const int c = c0 + cc;
        m[(64 + c) * 128 + (64 + r)] = f2bf(((r == c) ? 1.f : 0.f) + pk[cc]);
    }
}

// ---------------- main kernel: [128 rows x 128] @ M_t (K=128) ----------------
__global__ __launch_bounds__(256)
void gemm_kernel(const float4* __restrict__ x,
                 const unsigned short* __restrict__ mt,
                 float* __restrict__ out) {
    __shared__ __align__(16) char Xs[128 * 256];   // 128 rows x 128 bf16, swizzled

    const int tid  = threadIdx.x;
    const int t    = blockIdx.x & 7;
    const int rb   = blockIdx.x >> 3;
    const size_t rowbase = (size_t)rb * 128;

    const int lane = tid & 63, wid = tid >> 6;
    const int wm = wid >> 1, wn = wid & 1;          // 2x2 wave grid
    const int ln = lane & 15, lk = lane >> 4;

    // B fragments (M^T, L2-hot) -> VGPRs: b[fn][ks], 64 VGPR
    bf16x8 b[4][4];
    {
        const unsigned short* mtt = mt + t * 16384;
#pragma unroll
        for (int fn = 0; fn < 4; ++fn)
#pragma unroll
            for (int ks = 0; ks < 4; ++ks) {
                const int n = wn * 64 + fn * 16 + ln;
                const int k = ks * 32 + lk * 8;
                b[fn][ks] = *(const bf16x8*)(mtt + n * 128 + k);
            }
    }

    // stage X block -> LDS bf16, XOR-swizzled (byte ^= (row&7)<<4)
    {
        const int r0  = tid >> 4;          // 0..15
        const int seg = (tid >> 3) & 1;    // x1 / x2 half
        const int s2  = tid & 7;           // 16B slot within half
#pragma unroll
        for (int pass = 0; pass < 8; ++pass) {
            const int r = pass * 16 + r0;
            const size_t gidx = (rowbase + r) * 256 + seg * 128 + t * 16 + s2 * 2;
            const float4 v0 = x[gidx];
            const float4 v1 = x[gidx + 1];
            bf16x8 hv;
            hv[0] = (short)f2bf(v0.x); hv[1] = (short)f2bf(v0.y);
            hv[2] = (short)f2bf(v0.z); hv[3] = (short)f2bf(v0.w);
            hv[4] = (short)f2bf(v1.x); hv[5] = (short)f2bf(v1.y);
            hv[6] = (short)f2bf(v1.z); hv[7] = (short)f2bf(v1.w);
            int byte = r * 256 + seg * 128 + s2 * 16;
            byte ^= (r & 7) << 4;
            *(bf16x8*)(Xs + byte) = hv;
        }
    }
    __syncthreads();

    // MFMA: K=128 in 4 k-steps; acc[fm][fn] = 64 VGPR
    f32x4 acc[4][4];
#pragma unroll
    for (int p = 0; p < 4; ++p)
#pragma unroll
        for (int q = 0; q < 4; ++q) acc[p][q] = (f32x4)(0.f);

#pragma unroll
    for (int ks = 0; ks < 4; ++ks) {
        bf16x8 afr[4];
#pragma unroll
        for (int fm = 0; fm < 4; ++fm) {
            const int row = wm * 64 + fm * 16 + ln;
            int byte = row * 256 + ks * 64 + lk * 16;
            byte ^= (row & 7) << 4;
            afr[fm] = *(const bf16x8*)(Xs + byte);
        }
#pragma unroll
        for (int fm = 0; fm < 4; ++fm)
#pragma unroll
            for (int fn = 0; fn < 4; ++fn)
                acc[fm][fn] = __builtin_amdgcn_mfma_f32_16x16x32_bf16(
                    afr[fm], b[fn][ks], acc[fm][fn], 0, 0, 0);
    }

    // store: D lane map col=ln, row=lk*4+rr (guide-verified m89)
#pragma unroll
    for (int fm = 0; fm < 4; ++fm)
#pragma unroll
        for (int fn = 0; fn < 4; ++fn) {
            const int col = wn * 64 + fn * 16 + ln;           // 0..127
            const size_t cbase = (col < 64) ? (size_t)(t * 64 + col)
                                            : (size_t)(t * 64 + col + 448);
#pragma unroll
            for (int rr = 0; rr < 4; ++rr) {
                const size_t row = rowbase + wm * 64 + fm * 16 + lk * 4 + rr;
                out[row * 1024 + cbase] = acc[fm][fn][rr];
            }
        }
}

extern "C" void kernel_launch(void* const* d_in, const int* in_sizes, int n_in,
                              void* d_out, int out_size, void* d_ws, size_t ws_size,
                              hipStream_t stream) {
    const float4* x   = (const float4*)d_in[0];
    const float4* phi = (const float4*)d_in[1];
    const float4* psi = (const float4*)d_in[2];
    unsigned short* mt = (unsigned short*)d_ws;    // 8*128*128 bf16 = 256KB
    float* out = (float*)d_out;

    const int rows = in_sizes[0] / 1024;           // 65536
    prep_kernel<<<8, 256, 0, stream>>>(phi, psi, mt);
    gemm_kernel<<<(rows / 128) * 8, 256, 0, stream>>>(x, mt, out);
}

// Round 8
// 137.902 us; speedup vs baseline: 7.0227x; 1.0438x over previous
//
#include <hip/hip_runtime.h>

// Resonance tiling via fused block-GEMM on MFMA, pipelined streaming version.
// Math: per tile t, [y1,y2] = [x1,x2] * M_t, M_t = [[I,Psi],[Phi,I+Phi*Psi]]
// (128x128 bf16, built once by prep_kernel into d_ws).
// Round-7 lesson: one-shot blocks -> loads in flight only ~30% of lifetime,
// 3.6 TB/s. This round: persistent blocks grid-striding over 64-row chunks,
// T14 issue-early/write-late staging + double-buffered LDS, 1 barrier/chunk:
//   iter k: ds_write regs(k+1)->buf^1 ; issue loads(k+2)->regs ;
//           compute chunk k from buf ; __syncthreads ; swap.

typedef __attribute__((ext_vector_type(8))) short bf16x8;
typedef __attribute__((ext_vector_type(4))) float f32x4;

static __device__ __forceinline__ unsigned short f2bf(float f) {
    unsigned u = __builtin_bit_cast(unsigned, f);
    unsigned r = 0x7FFFu + ((u >> 16) & 1u);     // round-to-nearest-even
    return (unsigned short)((u + r) >> 16);
}

// ---------------- pre-kernel: build M_t^T (bf16) ----------------
__global__ __launch_bounds__(256)
void prep_kernel(const float4* __restrict__ phi,
                 const float4* __restrict__ psi,
                 unsigned short* __restrict__ mt) {
    __shared__ float Phi[64][64];
    __shared__ float Psi[64][64];
    const int t   = blockIdx.x;          // 0..7
    const int tid = threadIdx.x;
    const int i   = tid >> 4, j = tid & 15;

    {   // Hamilton 4x4 block (row-vec convention, matches reference)
        float4 w = phi[t * 256 + i * 16 + j];
        float a = w.x, b = w.y, c = w.z, d = w.w;
        Phi[4*i+0][4*j+0]= a; Phi[4*i+0][4*j+1]= b; Phi[4*i+0][4*j+2]= c; Phi[4*i+0][4*j+3]= d;
        Phi[4*i+1][4*j+0]=-b; Phi[4*i+1][4*j+1]= a; Phi[4*i+1][4*j+2]=-d; Phi[4*i+1][4*j+3]= c;
        Phi[4*i+2][4*j+0]=-c; Phi[4*i+2][4*j+1]= d; Phi[4*i+2][4*j+2]= a; Phi[4*i+2][4*j+3]=-b;
        Phi[4*i+3][4*j+0]=-d; Phi[4*i+3][4*j+1]=-c; Phi[4*i+3][4*j+2]= b; Phi[4*i+3][4*j+3]= a;
        float4 v = psi[(8 + t) * 256 + i * 16 + j];
        a = v.x; b = v.y; c = v.z; d = v.w;
        Psi[4*i+0][4*j+0]= a; Psi[4*i+0][4*j+1]= b; Psi[4*i+0][4*j+2]= c; Psi[4*i+0][4*j+3]= d;
        Psi[4*i+1][4*j+0]=-b; Psi[4*i+1][4*j+1]= a; Psi[4*i+1][4*j+2]=-d; Psi[4*i+1][4*j+3]= c;
        Psi[4*i+2][4*j+0]=-c; Psi[4*i+2][4*j+1]= d; Psi[4*i+2][4*j+2]= a; Psi[4*i+2][4*j+3]=-b;
        Psi[4*i+3][4*j+0]=-d; Psi[4*i+3][4*j+1]=-c; Psi[4*i+3][4*j+2]= b; Psi[4*i+3][4*j+3]= a;
    }
    __syncthreads();

    unsigned short* m = mt + t * 16384;   // MT[n][k] = M[k][n]
    for (int e = tid; e < 16384; e += 256) {
        const int n = e >> 7, k = e & 127;
        if (n >= 64 && k >= 64) continue;
        float v;
        if (k < 64 && n < 64)       v = (k == n) ? 1.f : 0.f;   // M11 = I
        else if (k >= 64)           v = Phi[k - 64][n];          // M21 = Phi
        else                        v = Psi[k][n - 64];          // M12 = Psi
        m[e] = f2bf(v);
    }
    // M22 = I + Phi@Psi
    const int r = tid & 63, c0 = (tid >> 6) * 16;
    float pk[16];
#pragma unroll
    for (int cc = 0; cc < 16; ++cc) pk[cc] = 0.f;
    for (int k = 0; k < 64; ++k) {
        const float fr = Phi[r][k];
#pragma unroll
        for (int cc = 0; cc < 16; ++cc) pk[cc] = fmaf(fr, Psi[k][c0 + cc], pk[cc]);
    }
#pragma unroll
    for (int cc = 0; cc < 16; ++cc) {
        const int c = c0 + cc;
        m[(64 + c) * 128 + (64 + r)] = f2bf(((r == c) ? 1.f : 0.f) + pk[cc]);
    }
}

// ---------------- main: persistent pipelined stream-GEMM ----------------
// chunk = 64 rows x (one tile's 128 K-cols). LDS: 2 x [64][128] bf16 swizzled.
__global__ __launch_bounds__(256)
void gemm_kernel(const float* __restrict__ x,
                 const unsigned short* __restrict__ mt,
                 float* __restrict__ out,
                 int nchunks) {
    __shared__ __align__(16) char Xs[2][16384];

    const int tid = threadIdx.x;
    const int t   = blockIdx.x & 7;
    const int cs  = gridDim.x >> 3;        // chunk stride (blocks per tile)

    const int lane = tid & 63, wid = tid >> 6;
    const int wm = wid >> 1, wn = wid & 1;          // 2x2 wave grid
    const int ln = lane & 15, lk = lane >> 4;

    // B fragments (M^T, L2-hot) -> 64 VGPR
    bf16x8 b[4][4];
    {
        const unsigned short* mtt = mt + t * 16384;
#pragma unroll
        for (int fn = 0; fn < 4; ++fn)
#pragma unroll
            for (int ks = 0; ks < 4; ++ks) {
                const int n = wn * 64 + fn * 16 + ln;
                const int k = ks * 32 + lk * 8;
                b[fn][ks] = *(const bf16x8*)(mtt + n * 128 + k);
            }
    }

    // staging map: thread covers row lr (0..63), k-quarter lq (32 f32)
    const int lr = tid >> 2, lq = tid & 3;
    const size_t colf = (size_t)t * 64 + (lq & 1) * 32 + (lq >> 1) * 512;
    const int wbyte = lr * 256 + lq * 64;

    float4 ld[8];
    auto stage_load = [&](int c) {
        const float* g = x + ((size_t)c * 64 + lr) * 1024 + colf;
#pragma unroll
        for (int i = 0; i < 8; ++i) ld[i] = *(const float4*)(g + i * 4);
    };
    auto stage_write = [&](int bsel) {
        char* base = Xs[bsel];
#pragma unroll
        for (int i = 0; i < 4; ++i) {
            bf16x8 hv;
            hv[0] = (short)f2bf(ld[2*i].x);   hv[1] = (short)f2bf(ld[2*i].y);
            hv[2] = (short)f2bf(ld[2*i].z);   hv[3] = (short)f2bf(ld[2*i].w);
            hv[4] = (short)f2bf(ld[2*i+1].x); hv[5] = (short)f2bf(ld[2*i+1].y);
            hv[6] = (short)f2bf(ld[2*i+1].z); hv[7] = (short)f2bf(ld[2*i+1].w);
            int byte = wbyte + i * 16;
            byte ^= (lr & 7) << 4;
            *(bf16x8*)(base + byte) = hv;
        }
    };

    const int cbase_col = t * 64 + wn * 64 + (wn ? 448 : 0);  // + fn*16 + ln

    int c  = blockIdx.x >> 3;
    // prologue: chunk c into buf0; issue loads for c+cs
    if (c < nchunks) { stage_load(c); stage_write(0); }
    __syncthreads();
    int c1 = c + cs;
    if (c1 < nchunks) stage_load(c1);

    int cur = 0;
    while (c < nchunks) {
        const int c2 = c1 + cs;
        if (c1 < nchunks) stage_write(cur ^ 1);   // regs(c1) -> other buf
        if (c2 < nchunks) stage_load(c2);         // issue next loads (in flight)

        // ---- compute chunk c from Xs[cur] ----
        f32x4 acc[2][4];
#pragma unroll
        for (int p = 0; p < 2; ++p)
#pragma unroll
            for (int q = 0; q < 4; ++q) acc[p][q] = (f32x4)(0.f);

        const char* base = Xs[cur];
#pragma unroll
        for (int ks = 0; ks < 4; ++ks) {
            bf16x8 afr[2];
#pragma unroll
            for (int fm = 0; fm < 2; ++fm) {
                const int row = wm * 32 + fm * 16 + ln;
                int byte = row * 256 + ks * 64 + lk * 16;
                byte ^= (row & 7) << 4;
                afr[fm] = *(const bf16x8*)(base + byte);
            }
#pragma unroll
            for (int fm = 0; fm < 2; ++fm)
#pragma unroll
                for (int fn = 0; fn < 4; ++fn)
                    acc[fm][fn] = __builtin_amdgcn_mfma_f32_16x16x32_bf16(
                        afr[fm], b[fn][ks], acc[fm][fn], 0, 0, 0);
        }

        // store: D lane map col=ln, row=lk*4+rr
#pragma unroll
        for (int fm = 0; fm < 2; ++fm)
#pragma unroll
            for (int fn = 0; fn < 4; ++fn) {
                const size_t cb = cbase_col + fn * 16 + ln;
#pragma unroll
                for (int rr = 0; rr < 4; ++rr) {
                    const size_t row = (size_t)c * 64 + wm * 32 + fm * 16 + lk * 4 + rr;
                    out[row * 1024 + cb] = acc[fm][fn][rr];
                }
            }

        __syncthreads();
        cur ^= 1; c = c1; c1 = c2;
    }
}

extern "C" void kernel_launch(void* const* d_in, const int* in_sizes, int n_in,
                              void* d_out, int out_size, void* d_ws, size_t ws_size,
                              hipStream_t stream) {
    const float* x    = (const float*)d_in[0];
    const float4* phi = (const float4*)d_in[1];
    const float4* psi = (const float4*)d_in[2];
    unsigned short* mt = (unsigned short*)d_ws;    // 8*128*128 bf16 = 256KB
    float* out = (float*)d_out;

    const int rows    = in_sizes[0] / 1024;        // 65536
    const int nchunks = rows / 64;                 // 1024
    const int blocks  = 8 * 96;                    // 3 blocks/CU, grid-stride

    prep_kernel<<<8, 256, 0, stream>>>(phi, psi, mt);
    gemm_kernel<<<blocks, 256, 0, stream>>>(x, mt, out, nchunks);
}